// Round 1
// baseline (9036.774 us; speedup 1.0000x reference)
//
#include <hip/hip_runtime.h>
#include <math.h>

#define NSENS 9
#define NEDGE 72
#define NPAIR 36
#define HDIM 128
#define NLAYER 4
#define FEPS 1e-8f

// Register-tiled GEMM: out[R][NC] = fetch[R][KTOT] @ W[KTOT][NC] + bias, optional relu,
// optional accumulate into dst (LDS). Thread owns 2 columns (c,c+1) and rows r0,r0+RSTEP,...
// fetch(r,kk) returns float4 of input[r][kk..kk+3] (kk multiple of 4).
template<int KTOT, int NC, int R, bool RELU, bool ACCUM, typename F>
__device__ __forceinline__ void mlp_gemm(const float* __restrict__ W,
                                         const float* __restrict__ bias,
                                         F fetch, float* __restrict__ dst)
{
    constexpr int HALF  = NC / 2;          // threads per row-group
    constexpr int RSTEP = 256 / HALF;      // 4 for NC=128, 8 for NC=64
    constexpr int NRMAX = (R + RSTEP - 1) / RSTEP;
    const int tid = threadIdx.x;
    const int c2  = tid & (HALF - 1);
    const int r0  = tid / HALF;
    const int c   = c2 * 2;
    float a0[NRMAX], a1[NRMAX];
#pragma unroll
    for (int i = 0; i < NRMAX; ++i) { a0[i] = 0.f; a1[i] = 0.f; }
    for (int kk = 0; kk < KTOT; kk += 4) {
        float2 w0 = *(const float2*)(W + (kk + 0) * NC + c);
        float2 w1 = *(const float2*)(W + (kk + 1) * NC + c);
        float2 w2 = *(const float2*)(W + (kk + 2) * NC + c);
        float2 w3 = *(const float2*)(W + (kk + 3) * NC + c);
        int i = 0;
#pragma unroll
        for (int r = r0; r < R; r += RSTEP, ++i) {
            float4 v = fetch(r, kk);   // wave-broadcast LDS read (all lanes same r,kk)
            a0[i] = fmaf(v.w, w3.x, fmaf(v.z, w2.x, fmaf(v.y, w1.x, fmaf(v.x, w0.x, a0[i]))));
            a1[i] = fmaf(v.w, w3.y, fmaf(v.z, w2.y, fmaf(v.y, w1.y, fmaf(v.x, w0.y, a1[i]))));
        }
    }
    const float b0 = bias[c], b1 = bias[c + 1];
    int i = 0;
#pragma unroll
    for (int r = r0; r < R; r += RSTEP, ++i) {
        float v0 = a0[i] + b0, v1 = a1[i] + b1;
        if (RELU) { v0 = fmaxf(v0, 0.f); v1 = fmaxf(v1, 0.f); }
        float* p = dst + r * NC + c;
        if (ACCUM) { p[0] += v0; p[1] += v1; }
        else       { p[0] = v0;  p[1] = v1; }
    }
}

// One block per graph; all activations LDS-resident. LDS ~62 KB -> 2 blocks/CU.
extern "C" __global__ void __launch_bounds__(256, 2)
gnn_fused(const float* __restrict__ x_nodes, const float* __restrict__ damage_locs,
          const float* __restrict__ enc_n_w, const float* __restrict__ enc_n_b,
          const float* __restrict__ enc_e_w1, const float* __restrict__ enc_e_b1,
          const float* __restrict__ enc_e_w2, const float* __restrict__ enc_e_b2,
          const float* __restrict__ edge_w1, const float* __restrict__ edge_b1,
          const float* __restrict__ edge_w2, const float* __restrict__ edge_b2,
          const float* __restrict__ node_w1, const float* __restrict__ node_b1,
          const float* __restrict__ node_w2, const float* __restrict__ node_b2,
          const float* __restrict__ dec_w1, const float* __restrict__ dec_b1,
          const float* __restrict__ dec_w2, const float* __restrict__ dec_b2,
          float* __restrict__ out)
{
    __shared__ __align__(16) float s_hn[NSENS * HDIM];   // node features
    __shared__ __align__(16) float s_he[NEDGE * HDIM];   // edge features
    __shared__ __align__(16) float s_t[24 * HDIM];       // MLP hidden (chunked)
    __shared__ __align__(16) float s_phys[NEDGE * 8];    // phys features, padded 6->8
    __shared__ __align__(16) float s_ew1[8 * HDIM];      // enc_e_w1 zero-padded to K=8
    __shared__ __align__(16) float s_sum[HDIM];          // sum of node features
    __shared__ float s_val[NEDGE];
    __shared__ float s_x[NSENS * 2];
    __shared__ float s_dmg[2];
    __shared__ int s_src[NEDGE], s_dst[NEDGE];

    const int g = blockIdx.x;
    const int tid = threadIdx.x;

    // ---- stage inputs / build static edge tables (replicates _build_edge_index) ----
    if (tid < NSENS * 2) s_x[tid] = x_nodes[g * NSENS * 2 + tid];
    if (tid < 2)         s_dmg[tid] = damage_locs[g * 2 + tid];
    if (tid < NEDGE) {
        int p = tid >> 1;
        int i = 0, rem = p, cnt = 8;
        while (rem >= cnt) { rem -= cnt; --cnt; ++i; }
        int j = i + 1 + rem;
        s_src[tid] = (tid & 1) ? j : i;   // even edge: i->j, odd edge: j->i
        s_dst[tid] = (tid & 1) ? i : j;
    }
    for (int idx = tid; idx < 8 * HDIM; idx += 256)
        s_ew1[idx] = (idx < 6 * HDIM) ? enc_e_w1[idx] : 0.f;
    __syncthreads();

    // ---- node encoder (K=2 linear) + edge phys features ----
    for (int idx = tid; idx < NSENS * HDIM; idx += 256) {
        int n = idx >> 7, h = idx & 127;
        s_hn[idx] = fmaf(s_x[2*n], enc_n_w[h],
                    fmaf(s_x[2*n+1], enc_n_w[HDIM + h], enc_n_b[h]));
    }
    if (tid < NEDGE) {
        const int si = s_src[tid], di = s_dst[tid];
        const float sx = s_x[2*si], sy = s_x[2*si+1];
        const float dx = s_x[2*di], dy = s_x[2*di+1];
        const float gx = s_dmg[0],  gy = s_dmg[1];
        const float vx = sx - dx, vy = sy - dy;
        const float vv = vx*vx + vy*vy;
        const float elen = sqrtf(vv + FEPS);
        const float l2 = fmaxf(vv, FEPS);
        float t = ((gx - sx) * (dx - sx) + (gy - sy) * (dy - sy)) / l2;
        t = fminf(fmaxf(t, 0.f), 1.f);
        const float px = sx + t * (dx - sx), py = sy + t * (dy - sy);
        const float d_path = sqrtf((gx-px)*(gx-px) + (gy-py)*(gy-py) + FEPS);
        const float d_tx   = sqrtf((sx-gx)*(sx-gx) + (sy-gy)*(sy-gy) + FEPS);
        const float d_rx   = sqrtf((dx-gx)*(dx-gx) + (dy-gy)*(dy-gy) + FEPS);
        float* ph = s_phys + tid * 8;
        ph[0]=vx; ph[1]=vy; ph[2]=elen; ph[3]=d_path; ph[4]=d_tx; ph[5]=d_rx;
        ph[6]=0.f; ph[7]=0.f;
    }
    __syncthreads();

    // ---- edge encoder: h_e = relu(phys@W1+b1)@W2+b2, 3 chunks of 24 edges ----
    for (int c0 = 0; c0 < NEDGE; c0 += 24) {
        auto fPhys = [&](int r, int kk) -> float4 {
            return *(const float4*)(s_phys + (c0 + r) * 8 + kk);
        };
        mlp_gemm<8, HDIM, 24, true, false>(s_ew1, enc_e_b1, fPhys, s_t);
        __syncthreads();
        auto fT = [&](int r, int kk) -> float4 {
            return *(const float4*)(s_t + r * HDIM + kk);
        };
        mlp_gemm<HDIM, HDIM, 24, false, false>(enc_e_w2, enc_e_b2, fT, s_he + c0 * HDIM);
        __syncthreads();
    }

    // ---- message-passing layers ----
    for (int l = 0; l < NLAYER; ++l) {
        const float* ew1 = edge_w1 + l * 3 * HDIM * HDIM;
        const float* eb1 = edge_b1 + l * HDIM;
        const float* ew2 = edge_w2 + l * HDIM * HDIM;
        const float* eb2 = edge_b2 + l * HDIM;
        // edge update: h_e += relu([h_src,h_dst,h_e]@W1+b1)@W2+b2
        for (int c0 = 0; c0 < NEDGE; c0 += 24) {
            auto fEin = [&](int r, int kk) -> float4 {
                const int e = c0 + r;
                if (kk < HDIM)
                    return *(const float4*)(s_hn + s_src[e] * HDIM + kk);
                else if (kk < 2 * HDIM)
                    return *(const float4*)(s_hn + s_dst[e] * HDIM + (kk - HDIM));
                else
                    return *(const float4*)(s_he + e * HDIM + (kk - 2 * HDIM));
            };
            mlp_gemm<3 * HDIM, HDIM, 24, true, false>(ew1, eb1, fEin, s_t);
            __syncthreads();
            auto fT = [&](int r, int kk) -> float4 {
                return *(const float4*)(s_t + r * HDIM + kk);
            };
            mlp_gemm<HDIM, HDIM, 24, false, true>(ew2, eb2, fT, s_he + c0 * HDIM);
            __syncthreads();
        }
        // node update: complete graph -> agg[n] = (sum_m h_n[m] - h_n[n]) / 8
        if (tid < HDIM) {
            float s = 0.f;
#pragma unroll
            for (int n = 0; n < NSENS; ++n) s += s_hn[n * HDIM + tid];
            s_sum[tid] = s;
        }
        __syncthreads();
        auto fNin = [&](int r, int kk) -> float4 {
            if (kk < HDIM) return *(const float4*)(s_hn + r * HDIM + kk);
            const int j = kk - HDIM;
            float4 a = *(const float4*)(s_hn + r * HDIM + j);
            float4 s = *(const float4*)(s_sum + j);
            return make_float4((s.x - a.x) * 0.125f, (s.y - a.y) * 0.125f,
                               (s.z - a.z) * 0.125f, (s.w - a.w) * 0.125f);
        };
        mlp_gemm<2 * HDIM, HDIM, NSENS, true, false>(node_w1 + l * 2 * HDIM * HDIM,
                                                     node_b1 + l * HDIM, fNin, s_t);
        __syncthreads();
        auto fTn = [&](int r, int kk) -> float4 {
            return *(const float4*)(s_t + r * HDIM + kk);
        };
        mlp_gemm<HDIM, HDIM, NSENS, false, true>(node_w2 + l * HDIM * HDIM,
                                                 node_b2 + l * HDIM, fTn, s_hn);
        __syncthreads();
    }

    // ---- decoder: sigmoid(relu(h_e@dec_w1+b1)@dec_w2+b2), 3 chunks of 24 ----
    for (int c0 = 0; c0 < NEDGE; c0 += 24) {
        auto fHe = [&](int r, int kk) -> float4 {
            return *(const float4*)(s_he + (c0 + r) * HDIM + kk);
        };
        mlp_gemm<HDIM, 64, 24, true, false>(dec_w1, dec_b1, fHe, s_t);  // s_t as [24][64]
        __syncthreads();
        if (tid < 24) {
            float acc = dec_b2[0];
            const float* tt = s_t + tid * 64;
#pragma unroll
            for (int k = 0; k < 64; ++k) acc = fmaf(tt[k], dec_w2[k], acc);
            s_val[c0 + tid] = 1.f / (1.f + expf(-acc));
        }
        __syncthreads();
    }
    // pair mean: edges (2p, 2p+1) are the two directions of pair p
    if (tid < NPAIR)
        out[g * NPAIR + tid] = 0.5f * (s_val[2 * tid] + s_val[2 * tid + 1]);
}

extern "C" void kernel_launch(void* const* d_in, const int* in_sizes, int n_in,
                              void* d_out, int out_size, void* d_ws, size_t ws_size,
                              hipStream_t stream) {
    const float* x_nodes     = (const float*)d_in[0];
    const float* damage_locs = (const float*)d_in[1];
    const float* enc_n_w  = (const float*)d_in[2];
    const float* enc_n_b  = (const float*)d_in[3];
    const float* enc_e_w1 = (const float*)d_in[4];
    const float* enc_e_b1 = (const float*)d_in[5];
    const float* enc_e_w2 = (const float*)d_in[6];
    const float* enc_e_b2 = (const float*)d_in[7];
    const float* edge_w1  = (const float*)d_in[8];
    const float* edge_b1  = (const float*)d_in[9];
    const float* edge_w2  = (const float*)d_in[10];
    const float* edge_b2  = (const float*)d_in[11];
    const float* node_w1  = (const float*)d_in[12];
    const float* node_b1  = (const float*)d_in[13];
    const float* node_w2  = (const float*)d_in[14];
    const float* node_b2  = (const float*)d_in[15];
    const float* dec_w1   = (const float*)d_in[16];
    const float* dec_b1   = (const float*)d_in[17];
    const float* dec_w2   = (const float*)d_in[18];
    const float* dec_b2   = (const float*)d_in[19];
    float* out = (float*)d_out;

    const int ngraph = in_sizes[1] / 2;   // damage_locs is [B,2]
    hipLaunchKernelGGL(gnn_fused, dim3(ngraph), dim3(256), 0, stream,
                       x_nodes, damage_locs,
                       enc_n_w, enc_n_b, enc_e_w1, enc_e_b1, enc_e_w2, enc_e_b2,
                       edge_w1, edge_b1, edge_w2, edge_b2,
                       node_w1, node_b1, node_w2, node_b2,
                       dec_w1, dec_b1, dec_w2, dec_b2, out);
}